// Round 19
// baseline (399.588 us; speedup 1.0000x reference)
//
#include <hip/hip_runtime.h>
#include <hip/hip_bf16.h>
#include <math.h>

typedef __bf16 bf16_t;
typedef __bf16 bf16x4 __attribute__((ext_vector_type(4)));
typedef short  s16x8  __attribute__((ext_vector_type(8)));
typedef float  f32x4  __attribute__((ext_vector_type(4)));
typedef float  f32x16 __attribute__((ext_vector_type(16)));

#define DEVINL __device__ __forceinline__

DEVINL void gload_lds16(const void* g, void* l) {
  __builtin_amdgcn_global_load_lds(
      (const __attribute__((address_space(1))) unsigned int*)g,
      (__attribute__((address_space(3))) unsigned int*)l, 16, 0, 0);
}

DEVINL f32x4 mfma16(s16x8 a, s16x8 b, f32x4 c) {
  return __builtin_amdgcn_mfma_f32_16x16x32_bf16(a, b, c, 0, 0, 0);
}

DEVINL f32x16 mfma32(s16x8 a, s16x8 b, f32x16 c) {
  return __builtin_amdgcn_mfma_f32_32x32x16_bf16(a, b, c, 0, 0, 0);
}

DEVINL float fexp2(float x) { return __builtin_amdgcn_exp2f(x); }  // native v_exp_f32

DEVINL unsigned pack_bf16(float lo, float hi) {
  union { bf16_t h[2]; unsigned u; } p;
  p.h[0] = (bf16_t)lo; p.h[1] = (bf16_t)hi;
  return p.u;
}

// ---------------- transpose + cast: W[K][N] f32 -> WT[N][K] bf16 ----------------
__global__ __launch_bounds__(256) void tcast_kernel(const float* __restrict__ W,
                                                    bf16_t* __restrict__ WT,
                                                    int K, int N) {
  __shared__ float tile[32][33];
  const int n0 = blockIdx.x * 32, k0 = blockIdx.y * 32;
  const int tx = threadIdx.x, ty = threadIdx.y;
#pragma unroll
  for (int j = 0; j < 4; ++j)
    tile[ty + j * 8][tx] = W[(size_t)(k0 + ty + j * 8) * N + (n0 + tx)];
  __syncthreads();
#pragma unroll
  for (int j = 0; j < 4; ++j)
    WT[(size_t)(n0 + ty + j * 8) * K + (k0 + tx)] = (bf16_t)tile[tx][ty + j * 8];
}

// ---------------- layernorm: f32 [rows][1024] -> bf16 ----------------
__global__ __launch_bounds__(256) void ln_kernel(const float* __restrict__ x,
                                                 const float* __restrict__ w,
                                                 const float* __restrict__ b,
                                                 bf16_t* __restrict__ out) {
  const int row = blockIdx.x, tid = threadIdx.x;
  const float4 v = ((const float4*)(x + (size_t)row * 1024))[tid];
  float s  = v.x + v.y + v.z + v.w;
  float s2 = v.x * v.x + v.y * v.y + v.z * v.z + v.w * v.w;
#pragma unroll
  for (int off = 32; off > 0; off >>= 1) {
    s  += __shfl_down(s, off);
    s2 += __shfl_down(s2, off);
  }
  __shared__ float red[8];
  const int wave = tid >> 6, lane = tid & 63;
  if (lane == 0) { red[wave] = s; red[4 + wave] = s2; }
  __syncthreads();
  s  = red[0] + red[1] + red[2] + red[3];
  s2 = red[4] + red[5] + red[6] + red[7];
  const float mu = s * (1.0f / 1024.0f);
  const float rs = rsqrtf(s2 * (1.0f / 1024.0f) - mu * mu + 1e-5f);
  const float4 wv = ((const float4*)w)[tid];
  const float4 bv = ((const float4*)b)[tid];
  bf16x4 o;
  o[0] = (bf16_t)((v.x - mu) * rs * wv.x + bv.x);
  o[1] = (bf16_t)((v.y - mu) * rs * wv.y + bv.y);
  o[2] = (bf16_t)((v.z - mu) * rs * wv.z + bv.z);
  o[3] = (bf16_t)((v.w - mu) * rs * wv.w + bv.w);
  ((bf16x4*)(out + (size_t)row * 1024))[tid] = o;
}

// ---------------- 128x128 GEMM, BK=64, TLP-based (r15 winner, unchanged) -----
// m-slice XCD chunking: each XCD owns 8 contiguous m-blocks x ALL n-cols.
// EPI 0: +bias -> bf16 | 1: +bias+resid -> f32 | 2: gelu -> bf16 | 3: qkv split
template <int EPI>
__global__ __launch_bounds__(256, 4) void gemm128b(const bf16_t* __restrict__ A,
                                                   const bf16_t* __restrict__ BT,
                                                   const float* __restrict__ bias,
                                                   const float* __restrict__ resid,
                                                   void* __restrict__ out,
                                                   void* __restrict__ out2,
                                                   int M, int N, int K) {
  __shared__ __align__(16) bf16_t sA[128 * 64];
  __shared__ __align__(16) bf16_t sB[128 * 64];
  const int tid = threadIdx.x;
  const int lane = tid & 63, wave = tid >> 6;
  const int wr = wave >> 1, wc = wave & 1;
  const int g = lane >> 4, lr = lane & 15;

  const int bid = blockIdx.x;
  const int xcd = bid & 7;
  const int i = bid >> 3;          // [0, 8*NB)
  const int m0 = (xcd * 8 + (i & 7)) * 128;
  const int n0 = (i >> 3) * 128;
  const bf16_t* Ab = A + (size_t)m0 * K;
  const bf16_t* Bb = BT + (size_t)n0 * K;

  f32x4 acc[4][4] = {};

  for (int kt = 0; kt < K; kt += 64) {
    __syncthreads();
#pragma unroll
    for (int q = 0; q < 4; ++q) {
      const int c = q * 256 + tid;
      const int r = c >> 3;
      const int j = (c & 7) ^ (r & 7);
      const size_t doff = (size_t)(q * 256 + wave * 64) * 8;
      gload_lds16(Ab + (size_t)r * K + kt + j * 8, sA + doff);
      gload_lds16(Bb + (size_t)r * K + kt + j * 8, sB + doff);
    }
    __syncthreads();
#pragma unroll
    for (int ks = 0; ks < 2; ++ks) {
      s16x8 af[4], bfr[4];
#pragma unroll
      for (int m = 0; m < 4; ++m) {
        const int r = wr * 64 + m * 16 + lr;
        af[m] = *(const s16x8*)&sA[r * 64 + (((ks << 2) + g) ^ (r & 7)) * 8];
      }
#pragma unroll
      for (int n = 0; n < 4; ++n) {
        const int r = wc * 64 + n * 16 + lr;
        bfr[n] = *(const s16x8*)&sB[r * 64 + (((ks << 2) + g) ^ (r & 7)) * 8];
      }
#pragma unroll
      for (int m = 0; m < 4; ++m)
#pragma unroll
        for (int n = 0; n < 4; ++n)
          acc[m][n] = mfma16(af[m], bfr[n], acc[m][n]);
    }
  }

#pragma unroll
  for (int m = 0; m < 4; ++m)
#pragma unroll
    for (int n = 0; n < 4; ++n) {
      const int col = n0 + wc * 64 + n * 16 + lr;
      const float bv = bias[col];
      const int rrow0 = m0 + wr * 64 + m * 16 + g * 4;
      if (EPI == 3 && col >= 2048) {
        const int col2 = col - 2048;
        bf16x4 pk;
#pragma unroll
        for (int i2 = 0; i2 < 4; ++i2) pk[i2] = (bf16_t)(acc[m][n][i2] + bv);
        const size_t didx =
            ((((size_t)(rrow0 >> 11)) * 16 + (col2 >> 6)) * 64 + (col2 & 63)) * 2048 +
            (rrow0 & 2047);
        *(bf16x4*)&((bf16_t*)out2)[didx] = pk;
      } else {
#pragma unroll
        for (int i2 = 0; i2 < 4; ++i2) {
          const int rrow = rrow0 + i2;
          float v = acc[m][n][i2] + bv;
          if (EPI == 1) {
            const size_t idx = (size_t)rrow * N + col;
            v += resid[idx];
            ((float*)out)[idx] = v;
          } else if (EPI == 2) {
            v = 0.5f * v * (1.0f + erff(v * 0.70710678118f));
            ((bf16_t*)out)[(size_t)rrow * N + col] = (bf16_t)v;
          } else if (EPI == 3) {
            ((bf16_t*)out)[(size_t)rrow * 2048 + col] = (bf16_t)v;
          } else {
            ((bf16_t*)out)[(size_t)rrow * N + col] = (bf16_t)v;
          }
        }
      }
    }
}

// ---------------- flash attention v12: v10 re-cut as 2-wave blocks ----------
// = v10 (32x32 MFMA, in-register P via permlane32_swap, fixed-shift softmax,
// single-buffer LDS), but QBLK=64 with 2 waves/block -> grid 2048: twice the
// independent barrier domains per CU, same total waves, same L2 chunking
// (256 blocks per XCD = 8 bh's).
__global__ __launch_bounds__(128) void flash_attn12(const bf16_t* __restrict__ qk,
                                                    const bf16_t* __restrict__ vt,
                                                    bf16_t* __restrict__ O) {
  const int S = 2048;
  const int bid = blockIdx.x;                 // 2048 blocks
  const int swz = (bid & 7) * 256 + (bid >> 3);
  const int bh = swz >> 5;                    // 64 (b,h)
  const int qt = swz & 31;                    // 32 q-tiles of 64 rows
  const int h = bh & 15;
  const size_t rowbase = (size_t)(bh >> 4) * S;
  const int tid = threadIdx.x, lane = tid & 63, wave = tid >> 6;  // wave in {0,1}
  const int ql = lane & 31;                   // q (and A-row) lane index
  const int H = lane >> 5;                    // lane half
  const int q0w = qt * 64 + wave * 32;
  const float c2 = 0.18033688f;               // 0.125 * log2(e)

  __shared__ __align__(16) bf16_t sK[64 * 64];     // [kv][d], XOR-swizzled chunks
  __shared__ __align__(16) bf16_t sVT[64 * 64];    // [d][kv], XOR-swizzled chunks

  const bf16_t* vtb = vt + (size_t)bh * 64 * 2048;

  // Q B-frags: frag ks holds Q[q0w+ql][d = 16ks + 8H + j]
  s16x8 qf[4];
  {
    const bf16_t* qrow = qk + (rowbase + q0w + ql) * 2048 + h * 64 + 8 * H;
#pragma unroll
    for (int ks = 0; ks < 4; ++ks) qf[ks] = *(const s16x8*)(qrow + 16 * ks);
  }

  f32x16 oa[2] = {};              // O^T frags: row d = 32df + (r&3)+8(r>>2)+4H, col q=ql
  float lrun = 0.0f;

  for (int kv0 = 0; kv0 < S; kv0 += 64) {
    __syncthreads();
    // stage K [64 kv][64 d] and VT [64 d][64 kv]; swizzled source, linear dest
    // 512 chunks each over 128 threads -> 4 per thread
#pragma unroll
    for (int p = 0; p < 4; ++p) {
      const int c = p * 128 + tid;
      const int r = c >> 3;
      const int pb = (c & 7) ^ (r & 7);
      char* dK = (char*)sK + (size_t)(p * 128 + wave * 64) * 16;
      char* dV = (char*)sVT + (size_t)(p * 128 + wave * 64) * 16;
      gload_lds16(qk + (rowbase + kv0 + r) * 2048 + 1024 + h * 64 + pb * 8, dK);
      gload_lds16(vtb + (size_t)r * 2048 + kv0 + pb * 8, dV);
    }
    __syncthreads();

    // swapped QK^T: sc[f][r] = S^T[kv = 32f + (r&3)+8(r>>2)+4H][q = ql]
    f32x16 sc[2] = {};
#pragma unroll
    for (int ks = 0; ks < 4; ++ks)
#pragma unroll
      for (int kvf = 0; kvf < 2; ++kvf) {
        const int R = kvf * 32 + ql;
        const s16x8 ak = *(const s16x8*)&sK[R * 64 + (((2 * ks + H) ^ (R & 7)) * 8)];
        sc[kvf] = mfma32(ak, qf[ks], sc[kvf]);
      }

    // fixed-shift softmax: P = exp2(s*c2 - 8); shift cancels in normalization
    float rsum = 0.0f;
#pragma unroll
    for (int f = 0; f < 2; ++f)
#pragma unroll
      for (int r = 0; r < 16; ++r) {
        const float pp = fexp2(fmaf(sc[f][r], c2, -8.0f));
        sc[f][r] = pp;
        rsum += pp;
      }
    rsum += __shfl_xor(rsum, 32);
    lrun += rsum;

    // PV with in-register P B-frags (permlane32_swap with (ql, ql^32) partner)
#pragma unroll
    for (int ks = 0; ks < 4; ++ks) {
      const int f = ks >> 1, rb = (ks & 1) * 8;
      unsigned A1 = pack_bf16(sc[f][rb + 0], sc[f][rb + 1]);
      unsigned A2 = pack_bf16(sc[f][rb + 2], sc[f][rb + 3]);
      unsigned B1 = pack_bf16(sc[f][rb + 4], sc[f][rb + 5]);
      unsigned B2 = pack_bf16(sc[f][rb + 6], sc[f][rb + 7]);
      asm("v_permlane32_swap_b32 %0, %1" : "+v"(A1), "+v"(B1));
      asm("v_permlane32_swap_b32 %0, %1" : "+v"(A2), "+v"(B2));
      union { unsigned u[4]; s16x8 v; } pf;
      pf.u[0] = A1; pf.u[1] = A2; pf.u[2] = B1; pf.u[3] = B2;
      const s16x8 pbf = pf.v;
#pragma unroll
      for (int df = 0; df < 2; ++df) {
        const int R = df * 32 + ql;
        const s16x8 va = *(const s16x8*)&sVT[R * 64 + (((2 * ks + H) ^ (R & 7)) * 8)];
        oa[df] = mfma32(va, pbf, oa[df]);
      }
    }
  }

  const float rl = 1.0f / lrun;
#pragma unroll
  for (int df = 0; df < 2; ++df)
#pragma unroll
    for (int rr = 0; rr < 4; ++rr) {
      bf16x4 ov;
#pragma unroll
      for (int e = 0; e < 4; ++e) ov[e] = (bf16_t)(oa[df][4 * rr + e] * rl);
      const int d0 = 32 * df + 8 * rr + 4 * H;
      *(bf16x4*)&O[(rowbase + q0w + ql) * 1024 + h * 64 + d0] = ov;
    }
}

// ---------------- launch ----------------
extern "C" void kernel_launch(void* const* d_in, const int* in_sizes, int n_in,
                              void* d_out, int out_size, void* d_ws, size_t ws_size,
                              hipStream_t stream) {
  const float* x    = (const float*)d_in[0];
  const float* ln1w = (const float*)d_in[1];
  const float* ln1b = (const float*)d_in[2];
  const float* Wqkv = (const float*)d_in[3];
  const float* bqkv = (const float*)d_in[4];
  const float* Wo   = (const float*)d_in[5];
  const float* bo   = (const float*)d_in[6];
  const float* ln2w = (const float*)d_in[7];
  const float* ln2b = (const float*)d_in[8];
  const float* fc1w = (const float*)d_in[9];
  const float* fc1b = (const float*)d_in[10];
  const float* fc2w = (const float*)d_in[11];
  const float* fc2b = (const float*)d_in[12];

  const int M = 8192;

  char* ws = (char*)d_ws;
  size_t off = 0;
  auto alloc = [&](size_t bytes) {
    char* p = ws + off;
    off += (bytes + 255) & ~(size_t)255;
    return p;
  };
  // persistent weights (bf16, transposed)
  bf16_t* WqkvT = (bf16_t*)alloc((size_t)3072 * 1024 * 2);   // 6 MB
  bf16_t* WoT   = (bf16_t*)alloc((size_t)1024 * 1024 * 2);   // 2 MB
  bf16_t* fc1T  = (bf16_t*)alloc((size_t)4096 * 1024 * 2);   // 8 MB
  bf16_t* fc2T  = (bf16_t*)alloc((size_t)1024 * 4096 * 2);   // 8 MB
  // activations
  bf16_t* h1    = (bf16_t*)alloc((size_t)M * 1024 * 2);      // 16 MB (reused as h2)
  bf16_t* qkQK  = (bf16_t*)alloc((size_t)M * 2048 * 2);      // 32 MB (attn region pt 1)
  bf16_t* vTg   = (bf16_t*)alloc((size_t)M * 1024 * 2);      // 16 MB (pt 2)
  bf16_t* attnO = (bf16_t*)alloc((size_t)M * 1024 * 2);      // 16 MB (pt 3)
  float*  x2    = (float*)alloc((size_t)M * 1024 * 4);       // 32 MB
  // aliases: lifetimes disjoint in stream order
  bf16_t* h2   = h1;     // h1 dead after QKV GEMM
  bf16_t* gbuf = qkQK;   // qkQK/vTg dead after attn, attnO dead after o-proj
  if (off > ws_size) return;  // ~136 MB required

  const dim3 tb(32, 8);
  tcast_kernel<<<dim3(96, 32), tb, 0, stream>>>(Wqkv, WqkvT, 1024, 3072);
  tcast_kernel<<<dim3(32, 32), tb, 0, stream>>>(Wo, WoT, 1024, 1024);
  tcast_kernel<<<dim3(128, 32), tb, 0, stream>>>(fc1w, fc1T, 1024, 4096);
  tcast_kernel<<<dim3(32, 128), tb, 0, stream>>>(fc2w, fc2T, 4096, 1024);

  ln_kernel<<<M, 256, 0, stream>>>(x, ln1w, ln1b, h1);

  gemm128b<3><<<dim3(1536), 256, 0, stream>>>(h1, WqkvT, bqkv, nullptr, qkQK, vTg, M, 3072, 1024);

  flash_attn12<<<dim3(2048), 128, 0, stream>>>(qkQK, vTg, attnO);

  gemm128b<1><<<dim3(512), 256, 0, stream>>>(attnO, WoT, bo, x, x2, nullptr, M, 1024, 1024);

  ln_kernel<<<M, 256, 0, stream>>>(x2, ln2w, ln2b, h2);

  gemm128b<2><<<dim3(2048), 256, 0, stream>>>(h2, fc1T, fc1b, nullptr, gbuf, nullptr, M, 4096, 1024);

  gemm128b<1><<<dim3(512), 256, 0, stream>>>(gbuf, fc2T, fc2b, x2, (float*)d_out, nullptr, M, 1024, 4096);
}

// Round 20
// 388.264 us; speedup vs baseline: 1.0292x; 1.0292x over previous
//
#include <hip/hip_runtime.h>
#include <hip/hip_bf16.h>
#include <math.h>

typedef __bf16 bf16_t;
typedef __bf16 bf16x4 __attribute__((ext_vector_type(4)));
typedef short  s16x8  __attribute__((ext_vector_type(8)));
typedef float  f32x4  __attribute__((ext_vector_type(4)));
typedef float  f32x16 __attribute__((ext_vector_type(16)));

#define DEVINL __device__ __forceinline__

DEVINL void gload_lds16(const void* g, void* l) {
  __builtin_amdgcn_global_load_lds(
      (const __attribute__((address_space(1))) unsigned int*)g,
      (__attribute__((address_space(3))) unsigned int*)l, 16, 0, 0);
}

DEVINL f32x4 mfma16(s16x8 a, s16x8 b, f32x4 c) {
  return __builtin_amdgcn_mfma_f32_16x16x32_bf16(a, b, c, 0, 0, 0);
}

DEVINL f32x16 mfma32(s16x8 a, s16x8 b, f32x16 c) {
  return __builtin_amdgcn_mfma_f32_32x32x16_bf16(a, b, c, 0, 0, 0);
}

DEVINL float fexp2(float x) { return __builtin_amdgcn_exp2f(x); }  // native v_exp_f32

DEVINL unsigned pack_bf16(float lo, float hi) {
  union { bf16_t h[2]; unsigned u; } p;
  p.h[0] = (bf16_t)lo; p.h[1] = (bf16_t)hi;
  return p.u;
}

// ---------------- transpose + cast: W[K][N] f32 -> WT[N][K] bf16 ----------------
__global__ __launch_bounds__(256) void tcast_kernel(const float* __restrict__ W,
                                                    bf16_t* __restrict__ WT,
                                                    int K, int N) {
  __shared__ float tile[32][33];
  const int n0 = blockIdx.x * 32, k0 = blockIdx.y * 32;
  const int tx = threadIdx.x, ty = threadIdx.y;
#pragma unroll
  for (int j = 0; j < 4; ++j)
    tile[ty + j * 8][tx] = W[(size_t)(k0 + ty + j * 8) * N + (n0 + tx)];
  __syncthreads();
#pragma unroll
  for (int j = 0; j < 4; ++j)
    WT[(size_t)(n0 + ty + j * 8) * K + (k0 + tx)] = (bf16_t)tile[tx][ty + j * 8];
}

// ---------------- layernorm: f32 [rows][1024] -> bf16 ----------------
__global__ __launch_bounds__(256) void ln_kernel(const float* __restrict__ x,
                                                 const float* __restrict__ w,
                                                 const float* __restrict__ b,
                                                 bf16_t* __restrict__ out) {
  const int row = blockIdx.x, tid = threadIdx.x;
  const float4 v = ((const float4*)(x + (size_t)row * 1024))[tid];
  float s  = v.x + v.y + v.z + v.w;
  float s2 = v.x * v.x + v.y * v.y + v.z * v.z + v.w * v.w;
#pragma unroll
  for (int off = 32; off > 0; off >>= 1) {
    s  += __shfl_down(s, off);
    s2 += __shfl_down(s2, off);
  }
  __shared__ float red[8];
  const int wave = tid >> 6, lane = tid & 63;
  if (lane == 0) { red[wave] = s; red[4 + wave] = s2; }
  __syncthreads();
  s  = red[0] + red[1] + red[2] + red[3];
  s2 = red[4] + red[5] + red[6] + red[7];
  const float mu = s * (1.0f / 1024.0f);
  const float rs = rsqrtf(s2 * (1.0f / 1024.0f) - mu * mu + 1e-5f);
  const float4 wv = ((const float4*)w)[tid];
  const float4 bv = ((const float4*)b)[tid];
  bf16x4 o;
  o[0] = (bf16_t)((v.x - mu) * rs * wv.x + bv.x);
  o[1] = (bf16_t)((v.y - mu) * rs * wv.y + bv.y);
  o[2] = (bf16_t)((v.z - mu) * rs * wv.z + bv.z);
  o[3] = (bf16_t)((v.w - mu) * rs * wv.w + bv.w);
  ((bf16x4*)(out + (size_t)row * 1024))[tid] = o;
}

// ---------------- 128x128 GEMM, BK=64, TLP-based (r15 winner, unchanged) -----
// m-slice XCD chunking: each XCD owns 8 contiguous m-blocks x ALL n-cols.
// EPI 0: +bias -> bf16 | 1: +bias+resid -> f32 | 2: gelu -> bf16 | 3: qkv split
template <int EPI>
__global__ __launch_bounds__(256, 4) void gemm128b(const bf16_t* __restrict__ A,
                                                   const bf16_t* __restrict__ BT,
                                                   const float* __restrict__ bias,
                                                   const float* __restrict__ resid,
                                                   void* __restrict__ out,
                                                   void* __restrict__ out2,
                                                   int M, int N, int K) {
  __shared__ __align__(16) bf16_t sA[128 * 64];
  __shared__ __align__(16) bf16_t sB[128 * 64];
  const int tid = threadIdx.x;
  const int lane = tid & 63, wave = tid >> 6;
  const int wr = wave >> 1, wc = wave & 1;
  const int g = lane >> 4, lr = lane & 15;

  const int bid = blockIdx.x;
  const int xcd = bid & 7;
  const int i = bid >> 3;          // [0, 8*NB)
  const int m0 = (xcd * 8 + (i & 7)) * 128;
  const int n0 = (i >> 3) * 128;
  const bf16_t* Ab = A + (size_t)m0 * K;
  const bf16_t* Bb = BT + (size_t)n0 * K;

  f32x4 acc[4][4] = {};

  for (int kt = 0; kt < K; kt += 64) {
    __syncthreads();
#pragma unroll
    for (int q = 0; q < 4; ++q) {
      const int c = q * 256 + tid;
      const int r = c >> 3;
      const int j = (c & 7) ^ (r & 7);
      const size_t doff = (size_t)(q * 256 + wave * 64) * 8;
      gload_lds16(Ab + (size_t)r * K + kt + j * 8, sA + doff);
      gload_lds16(Bb + (size_t)r * K + kt + j * 8, sB + doff);
    }
    __syncthreads();
#pragma unroll
    for (int ks = 0; ks < 2; ++ks) {
      s16x8 af[4], bfr[4];
#pragma unroll
      for (int m = 0; m < 4; ++m) {
        const int r = wr * 64 + m * 16 + lr;
        af[m] = *(const s16x8*)&sA[r * 64 + (((ks << 2) + g) ^ (r & 7)) * 8];
      }
#pragma unroll
      for (int n = 0; n < 4; ++n) {
        const int r = wc * 64 + n * 16 + lr;
        bfr[n] = *(const s16x8*)&sB[r * 64 + (((ks << 2) + g) ^ (r & 7)) * 8];
      }
#pragma unroll
      for (int m = 0; m < 4; ++m)
#pragma unroll
        for (int n = 0; n < 4; ++n)
          acc[m][n] = mfma16(af[m], bfr[n], acc[m][n]);
    }
  }

#pragma unroll
  for (int m = 0; m < 4; ++m)
#pragma unroll
    for (int n = 0; n < 4; ++n) {
      const int col = n0 + wc * 64 + n * 16 + lr;
      const float bv = bias[col];
      const int rrow0 = m0 + wr * 64 + m * 16 + g * 4;
      if (EPI == 3 && col >= 2048) {
        const int col2 = col - 2048;
        bf16x4 pk;
#pragma unroll
        for (int i2 = 0; i2 < 4; ++i2) pk[i2] = (bf16_t)(acc[m][n][i2] + bv);
        const size_t didx =
            ((((size_t)(rrow0 >> 11)) * 16 + (col2 >> 6)) * 64 + (col2 & 63)) * 2048 +
            (rrow0 & 2047);
        *(bf16x4*)&((bf16_t*)out2)[didx] = pk;
      } else {
#pragma unroll
        for (int i2 = 0; i2 < 4; ++i2) {
          const int rrow = rrow0 + i2;
          float v = acc[m][n][i2] + bv;
          if (EPI == 1) {
            const size_t idx = (size_t)rrow * N + col;
            v += resid[idx];
            ((float*)out)[idx] = v;
          } else if (EPI == 2) {
            v = 0.5f * v * (1.0f + erff(v * 0.70710678118f));
            ((bf16_t*)out)[(size_t)rrow * N + col] = (bf16_t)v;
          } else if (EPI == 3) {
            ((bf16_t*)out)[(size_t)rrow * 2048 + col] = (bf16_t)v;
          } else {
            ((bf16_t*)out)[(size_t)rrow * N + col] = (bf16_t)v;
          }
        }
      }
    }
}

// ---------------- flash attention v13: q-subtile pairing (QBLK=256) ----------
// = v10 core (32x32 MFMA, in-register P, fixed-shift softmax, single-buffer
// LDS), but each wave handles TWO 32-q subtiles sharing every K/V fragment
// load: per-q-row staging VMEM, barriers and LDS b128 reads all halve.
// Grid 512 (64 blocks per XCD chunk = 8 bh x 8 q-tiles; same L2 set).
__global__ __launch_bounds__(256) void flash_attn13(const bf16_t* __restrict__ qk,
                                                    const bf16_t* __restrict__ vt,
                                                    bf16_t* __restrict__ O) {
  const int S = 2048;
  const int bid = blockIdx.x;                 // 512 blocks
  const int swz = (bid & 7) * 64 + (bid >> 3);
  const int bh = swz >> 3;                    // 64 (b,h)
  const int qt = swz & 7;                     // 8 q-tiles of 256 rows
  const int h = bh & 15;
  const size_t rowbase = (size_t)(bh >> 4) * S;
  const int tid = threadIdx.x, lane = tid & 63, wave = tid >> 6;
  const int ql = lane & 31;                   // q (and A-row) lane index
  const int H = lane >> 5;                    // lane half
  const int q0w = qt * 256 + wave * 64;       // wave owns [q0w, q0w+64)
  const float c2 = 0.18033688f;               // 0.125 * log2(e)

  __shared__ __align__(16) bf16_t sK[64 * 64];     // [kv][d], XOR-swizzled chunks
  __shared__ __align__(16) bf16_t sVT[64 * 64];    // [d][kv], XOR-swizzled chunks

  const bf16_t* vtb = vt + (size_t)bh * 64 * 2048;

  // Q B-frags for both subtiles: qf[sub][ks] = Q[q0w+32sub+ql][d=16ks+8H+j]
  s16x8 qf0[4], qf1[4];
  {
    const bf16_t* qrow0 = qk + (rowbase + q0w + ql) * 2048 + h * 64 + 8 * H;
    const bf16_t* qrow1 = qrow0 + (size_t)32 * 2048;
#pragma unroll
    for (int ks = 0; ks < 4; ++ks) {
      qf0[ks] = *(const s16x8*)(qrow0 + 16 * ks);
      qf1[ks] = *(const s16x8*)(qrow1 + 16 * ks);
    }
  }

  f32x16 oa0[2] = {}, oa1[2] = {};  // per subtile: O^T frags
  float lrun0 = 0.0f, lrun1 = 0.0f;

  for (int kv0 = 0; kv0 < S; kv0 += 64) {
    __syncthreads();
    // stage K [64 kv][64 d] and VT [64 d][64 kv]; swizzled source, linear dest
#pragma unroll
    for (int p = 0; p < 2; ++p) {
      const int c = p * 256 + wave * 64 + lane;
      const int r = c >> 3;
      const int pb = (c & 7) ^ (r & 7);
      char* dK = (char*)sK + (size_t)(p * 256 + wave * 64) * 16;
      char* dV = (char*)sVT + (size_t)(p * 256 + wave * 64) * 16;
      gload_lds16(qk + (rowbase + kv0 + r) * 2048 + 1024 + h * 64 + pb * 8, dK);
      gload_lds16(vtb + (size_t)r * 2048 + kv0 + pb * 8, dV);
    }
    __syncthreads();

    // swapped QK^T: each ak load feeds BOTH subtiles
    f32x16 sc0[2] = {}, sc1[2] = {};
#pragma unroll
    for (int ks = 0; ks < 4; ++ks)
#pragma unroll
      for (int kvf = 0; kvf < 2; ++kvf) {
        const int R = kvf * 32 + ql;
        const s16x8 ak = *(const s16x8*)&sK[R * 64 + (((2 * ks + H) ^ (R & 7)) * 8)];
        if (kvf == 0) { sc0[0] = mfma32(ak, qf0[ks], sc0[0]); sc1[0] = mfma32(ak, qf1[ks], sc1[0]); }
        else          { sc0[1] = mfma32(ak, qf0[ks], sc0[1]); sc1[1] = mfma32(ak, qf1[ks], sc1[1]); }
      }

    // fixed-shift softmax per subtile
    float rs0 = 0.0f, rs1 = 0.0f;
#pragma unroll
    for (int f = 0; f < 2; ++f)
#pragma unroll
      for (int r = 0; r < 16; ++r) {
        const float p0 = fexp2(fmaf(sc0[f][r], c2, -8.0f));
        const float p1 = fexp2(fmaf(sc1[f][r], c2, -8.0f));
        sc0[f][r] = p0; rs0 += p0;
        sc1[f][r] = p1; rs1 += p1;
      }
    rs0 += __shfl_xor(rs0, 32);
    rs1 += __shfl_xor(rs1, 32);
    lrun0 += rs0;
    lrun1 += rs1;

    // PV: each va load feeds BOTH subtiles; in-register P via permlane32_swap
#pragma unroll
    for (int ks = 0; ks < 4; ++ks) {
      const int f = ks >> 1, rb = (ks & 1) * 8;
      unsigned A1 = pack_bf16(sc0[f][rb + 0], sc0[f][rb + 1]);
      unsigned A2 = pack_bf16(sc0[f][rb + 2], sc0[f][rb + 3]);
      unsigned B1 = pack_bf16(sc0[f][rb + 4], sc0[f][rb + 5]);
      unsigned B2 = pack_bf16(sc0[f][rb + 6], sc0[f][rb + 7]);
      asm("v_permlane32_swap_b32 %0, %1" : "+v"(A1), "+v"(B1));
      asm("v_permlane32_swap_b32 %0, %1" : "+v"(A2), "+v"(B2));
      unsigned C1 = pack_bf16(sc1[f][rb + 0], sc1[f][rb + 1]);
      unsigned C2 = pack_bf16(sc1[f][rb + 2], sc1[f][rb + 3]);
      unsigned D1 = pack_bf16(sc1[f][rb + 4], sc1[f][rb + 5]);
      unsigned D2 = pack_bf16(sc1[f][rb + 6], sc1[f][rb + 7]);
      asm("v_permlane32_swap_b32 %0, %1" : "+v"(C1), "+v"(D1));
      asm("v_permlane32_swap_b32 %0, %1" : "+v"(C2), "+v"(D2));
      union { unsigned u[4]; s16x8 v; } pf0, pf1;
      pf0.u[0] = A1; pf0.u[1] = A2; pf0.u[2] = B1; pf0.u[3] = B2;
      pf1.u[0] = C1; pf1.u[1] = C2; pf1.u[2] = D1; pf1.u[3] = D2;
      const s16x8 pb0 = pf0.v, pb1 = pf1.v;
#pragma unroll
      for (int df = 0; df < 2; ++df) {
        const int R = df * 32 + ql;
        const s16x8 va = *(const s16x8*)&sVT[R * 64 + (((2 * ks + H) ^ (R & 7)) * 8)];
        if (df == 0) { oa0[0] = mfma32(va, pb0, oa0[0]); oa1[0] = mfma32(va, pb1, oa1[0]); }
        else         { oa0[1] = mfma32(va, pb0, oa0[1]); oa1[1] = mfma32(va, pb1, oa1[1]); }
      }
    }
  }

  const float rl0 = 1.0f / lrun0;
  const float rl1 = 1.0f / lrun1;
#pragma unroll
  for (int df = 0; df < 2; ++df)
#pragma unroll
    for (int rr = 0; rr < 4; ++rr) {
      bf16x4 o0, o1;
#pragma unroll
      for (int e = 0; e < 4; ++e) {
        o0[e] = (bf16_t)(oa0[df][4 * rr + e] * rl0);
        o1[e] = (bf16_t)(oa1[df][4 * rr + e] * rl1);
      }
      const int d0 = 32 * df + 8 * rr + 4 * H;
      *(bf16x4*)&O[(rowbase + q0w + ql) * 1024 + h * 64 + d0] = o0;
      *(bf16x4*)&O[(rowbase + q0w + 32 + ql) * 1024 + h * 64 + d0] = o1;
    }
}

// ---------------- launch ----------------
extern "C" void kernel_launch(void* const* d_in, const int* in_sizes, int n_in,
                              void* d_out, int out_size, void* d_ws, size_t ws_size,
                              hipStream_t stream) {
  const float* x    = (const float*)d_in[0];
  const float* ln1w = (const float*)d_in[1];
  const float* ln1b = (const float*)d_in[2];
  const float* Wqkv = (const float*)d_in[3];
  const float* bqkv = (const float*)d_in[4];
  const float* Wo   = (const float*)d_in[5];
  const float* bo   = (const float*)d_in[6];
  const float* ln2w = (const float*)d_in[7];
  const float* ln2b = (const float*)d_in[8];
  const float* fc1w = (const float*)d_in[9];
  const float* fc1b = (const float*)d_in[10];
  const float* fc2w = (const float*)d_in[11];
  const float* fc2b = (const float*)d_in[12];

  const int M = 8192;

  char* ws = (char*)d_ws;
  size_t off = 0;
  auto alloc = [&](size_t bytes) {
    char* p = ws + off;
    off += (bytes + 255) & ~(size_t)255;
    return p;
  };
  // persistent weights (bf16, transposed)
  bf16_t* WqkvT = (bf16_t*)alloc((size_t)3072 * 1024 * 2);   // 6 MB
  bf16_t* WoT   = (bf16_t*)alloc((size_t)1024 * 1024 * 2);   // 2 MB
  bf16_t* fc1T  = (bf16_t*)alloc((size_t)4096 * 1024 * 2);   // 8 MB
  bf16_t* fc2T  = (bf16_t*)alloc((size_t)1024 * 4096 * 2);   // 8 MB
  // activations
  bf16_t* h1    = (bf16_t*)alloc((size_t)M * 1024 * 2);      // 16 MB (reused as h2)
  bf16_t* qkQK  = (bf16_t*)alloc((size_t)M * 2048 * 2);      // 32 MB (attn region pt 1)
  bf16_t* vTg   = (bf16_t*)alloc((size_t)M * 1024 * 2);      // 16 MB (pt 2)
  bf16_t* attnO = (bf16_t*)alloc((size_t)M * 1024 * 2);      // 16 MB (pt 3)
  float*  x2    = (float*)alloc((size_t)M * 1024 * 4);       // 32 MB
  // aliases: lifetimes disjoint in stream order
  bf16_t* h2   = h1;     // h1 dead after QKV GEMM
  bf16_t* gbuf = qkQK;   // qkQK/vTg dead after attn, attnO dead after o-proj
  if (off > ws_size) return;  // ~136 MB required

  const dim3 tb(32, 8);
  tcast_kernel<<<dim3(96, 32), tb, 0, stream>>>(Wqkv, WqkvT, 1024, 3072);
  tcast_kernel<<<dim3(32, 32), tb, 0, stream>>>(Wo, WoT, 1024, 1024);
  tcast_kernel<<<dim3(128, 32), tb, 0, stream>>>(fc1w, fc1T, 1024, 4096);
  tcast_kernel<<<dim3(32, 128), tb, 0, stream>>>(fc2w, fc2T, 4096, 1024);

  ln_kernel<<<M, 256, 0, stream>>>(x, ln1w, ln1b, h1);

  gemm128b<3><<<dim3(1536), 256, 0, stream>>>(h1, WqkvT, bqkv, nullptr, qkQK, vTg, M, 3072, 1024);

  flash_attn13<<<dim3(512), 256, 0, stream>>>(qkQK, vTg, attnO);

  gemm128b<1><<<dim3(512), 256, 0, stream>>>(attnO, WoT, bo, x, x2, nullptr, M, 1024, 1024);

  ln_kernel<<<M, 256, 0, stream>>>(x2, ln2w, ln2b, h2);

  gemm128b<2><<<dim3(2048), 256, 0, stream>>>(h2, fc1T, fc1b, nullptr, gbuf, nullptr, M, 4096, 1024);

  gemm128b<1><<<dim3(512), 256, 0, stream>>>(gbuf, fc2T, fc2b, x2, (float*)d_out, nullptr, M, 1024, 4096);
}

// Round 21
// 378.132 us; speedup vs baseline: 1.0567x; 1.0268x over previous
//
#include <hip/hip_runtime.h>
#include <hip/hip_bf16.h>
#include <math.h>

typedef __bf16 bf16_t;
typedef __bf16 bf16x4 __attribute__((ext_vector_type(4)));
typedef short  s16x8  __attribute__((ext_vector_type(8)));
typedef float  f32x4  __attribute__((ext_vector_type(4)));
typedef float  f32x16 __attribute__((ext_vector_type(16)));

#define DEVINL __device__ __forceinline__

DEVINL void gload_lds16(const void* g, void* l) {
  __builtin_amdgcn_global_load_lds(
      (const __attribute__((address_space(1))) unsigned int*)g,
      (__attribute__((address_space(3))) unsigned int*)l, 16, 0, 0);
}

DEVINL f32x4 mfma16(s16x8 a, s16x8 b, f32x4 c) {
  return __builtin_amdgcn_mfma_f32_16x16x32_bf16(a, b, c, 0, 0, 0);
}

DEVINL f32x16 mfma32(s16x8 a, s16x8 b, f32x16 c) {
  return __builtin_amdgcn_mfma_f32_32x32x16_bf16(a, b, c, 0, 0, 0);
}

DEVINL float fexp2(float x) { return __builtin_amdgcn_exp2f(x); }  // native v_exp_f32

DEVINL unsigned pack_bf16(float lo, float hi) {
  union { bf16_t h[2]; unsigned u; } p;
  p.h[0] = (bf16_t)lo; p.h[1] = (bf16_t)hi;
  return p.u;
}

// ---------------- transpose + cast: W[K][N] f32 -> WT[N][K] bf16 ----------------
__global__ __launch_bounds__(256) void tcast_kernel(const float* __restrict__ W,
                                                    bf16_t* __restrict__ WT,
                                                    int K, int N) {
  __shared__ float tile[32][33];
  const int n0 = blockIdx.x * 32, k0 = blockIdx.y * 32;
  const int tx = threadIdx.x, ty = threadIdx.y;
#pragma unroll
  for (int j = 0; j < 4; ++j)
    tile[ty + j * 8][tx] = W[(size_t)(k0 + ty + j * 8) * N + (n0 + tx)];
  __syncthreads();
#pragma unroll
  for (int j = 0; j < 4; ++j)
    WT[(size_t)(n0 + ty + j * 8) * K + (k0 + tx)] = (bf16_t)tile[tx][ty + j * 8];
}

// ---------------- layernorm: f32 [rows][1024] -> bf16 ----------------
__global__ __launch_bounds__(256) void ln_kernel(const float* __restrict__ x,
                                                 const float* __restrict__ w,
                                                 const float* __restrict__ b,
                                                 bf16_t* __restrict__ out) {
  const int row = blockIdx.x, tid = threadIdx.x;
  const float4 v = ((const float4*)(x + (size_t)row * 1024))[tid];
  float s  = v.x + v.y + v.z + v.w;
  float s2 = v.x * v.x + v.y * v.y + v.z * v.z + v.w * v.w;
#pragma unroll
  for (int off = 32; off > 0; off >>= 1) {
    s  += __shfl_down(s, off);
    s2 += __shfl_down(s2, off);
  }
  __shared__ float red[8];
  const int wave = tid >> 6, lane = tid & 63;
  if (lane == 0) { red[wave] = s; red[4 + wave] = s2; }
  __syncthreads();
  s  = red[0] + red[1] + red[2] + red[3];
  s2 = red[4] + red[5] + red[6] + red[7];
  const float mu = s * (1.0f / 1024.0f);
  const float rs = rsqrtf(s2 * (1.0f / 1024.0f) - mu * mu + 1e-5f);
  const float4 wv = ((const float4*)w)[tid];
  const float4 bv = ((const float4*)b)[tid];
  bf16x4 o;
  o[0] = (bf16_t)((v.x - mu) * rs * wv.x + bv.x);
  o[1] = (bf16_t)((v.y - mu) * rs * wv.y + bv.y);
  o[2] = (bf16_t)((v.z - mu) * rs * wv.z + bv.z);
  o[3] = (bf16_t)((v.w - mu) * rs * wv.w + bv.w);
  ((bf16x4*)(out + (size_t)row * 1024))[tid] = o;
}

// ---------------- 128x128 GEMM, BK=64, TLP-based (r15 winner) ----------------
// m-slice XCD chunking: each XCD owns 8 contiguous m-blocks x ALL n-cols.
// EPI 0: +bias -> bf16 | 1: +bias+resid -> f32 | 2: gelu -> bf16 | 3: qkv split
template <int EPI>
__global__ __launch_bounds__(256, 4) void gemm128b(const bf16_t* __restrict__ A,
                                                   const bf16_t* __restrict__ BT,
                                                   const float* __restrict__ bias,
                                                   const float* __restrict__ resid,
                                                   void* __restrict__ out,
                                                   void* __restrict__ out2,
                                                   int M, int N, int K) {
  __shared__ __align__(16) bf16_t sA[128 * 64];
  __shared__ __align__(16) bf16_t sB[128 * 64];
  const int tid = threadIdx.x;
  const int lane = tid & 63, wave = tid >> 6;
  const int wr = wave >> 1, wc = wave & 1;
  const int g = lane >> 4, lr = lane & 15;

  const int bid = blockIdx.x;
  const int xcd = bid & 7;
  const int i = bid >> 3;          // [0, 8*NB)
  const int m0 = (xcd * 8 + (i & 7)) * 128;
  const int n0 = (i >> 3) * 128;
  const bf16_t* Ab = A + (size_t)m0 * K;
  const bf16_t* Bb = BT + (size_t)n0 * K;

  f32x4 acc[4][4] = {};

  for (int kt = 0; kt < K; kt += 64) {
    __syncthreads();
#pragma unroll
    for (int q = 0; q < 4; ++q) {
      const int c = q * 256 + tid;
      const int r = c >> 3;
      const int j = (c & 7) ^ (r & 7);
      const size_t doff = (size_t)(q * 256 + wave * 64) * 8;
      gload_lds16(Ab + (size_t)r * K + kt + j * 8, sA + doff);
      gload_lds16(Bb + (size_t)r * K + kt + j * 8, sB + doff);
    }
    __syncthreads();
#pragma unroll
    for (int ks = 0; ks < 2; ++ks) {
      s16x8 af[4], bfr[4];
#pragma unroll
      for (int m = 0; m < 4; ++m) {
        const int r = wr * 64 + m * 16 + lr;
        af[m] = *(const s16x8*)&sA[r * 64 + (((ks << 2) + g) ^ (r & 7)) * 8];
      }
#pragma unroll
      for (int n = 0; n < 4; ++n) {
        const int r = wc * 64 + n * 16 + lr;
        bfr[n] = *(const s16x8*)&sB[r * 64 + (((ks << 2) + g) ^ (r & 7)) * 8];
      }
#pragma unroll
      for (int m = 0; m < 4; ++m)
#pragma unroll
        for (int n = 0; n < 4; ++n)
          acc[m][n] = mfma16(af[m], bfr[n], acc[m][n]);
    }
  }

#pragma unroll
  for (int m = 0; m < 4; ++m)
#pragma unroll
    for (int n = 0; n < 4; ++n) {
      const int col = n0 + wc * 64 + n * 16 + lr;
      const float bv = bias[col];
      const int rrow0 = m0 + wr * 64 + m * 16 + g * 4;
      if (EPI == 3 && col >= 2048) {
        const int col2 = col - 2048;
        bf16x4 pk;
#pragma unroll
        for (int i2 = 0; i2 < 4; ++i2) pk[i2] = (bf16_t)(acc[m][n][i2] + bv);
        const size_t didx =
            ((((size_t)(rrow0 >> 11)) * 16 + (col2 >> 6)) * 64 + (col2 & 63)) * 2048 +
            (rrow0 & 2047);
        *(bf16x4*)&((bf16_t*)out2)[didx] = pk;
      } else {
#pragma unroll
        for (int i2 = 0; i2 < 4; ++i2) {
          const int rrow = rrow0 + i2;
          float v = acc[m][n][i2] + bv;
          if (EPI == 1) {
            const size_t idx = (size_t)rrow * N + col;
            v += resid[idx];
            ((float*)out)[idx] = v;
          } else if (EPI == 2) {
            v = 0.5f * v * (1.0f + erff(v * 0.70710678118f));
            ((bf16_t*)out)[(size_t)rrow * N + col] = (bf16_t)v;
          } else if (EPI == 3) {
            ((bf16_t*)out)[(size_t)rrow * 2048 + col] = (bf16_t)v;
          } else {
            ((bf16_t*)out)[(size_t)rrow * N + col] = (bf16_t)v;
          }
        }
      }
    }
}

// ---------------- flash attention v10: fixed-shift softmax (r17 winner) -------
// 32x32 MFMA, QBLK=128 (4 waves), single-buffer LDS, in-register P via
// permlane32_swap, fixed-shift softmax P = exp2(s*c2 - 8) (shift cancels in
// normalization; scores bounded for LN'd inputs).
__global__ __launch_bounds__(256) void flash_attn10(const bf16_t* __restrict__ qk,
                                                    const bf16_t* __restrict__ vt,
                                                    bf16_t* __restrict__ O) {
  const int S = 2048;
  const int bid = blockIdx.x;                 // 1024 blocks
  const int swz = (bid & 7) * 128 + (bid >> 3);
  const int bh = swz >> 4;                    // 64 (b,h)
  const int qt = swz & 15;                    // 16 q-tiles of 128 rows
  const int h = bh & 15;
  const size_t rowbase = (size_t)(bh >> 4) * S;
  const int tid = threadIdx.x, lane = tid & 63, wave = tid >> 6;
  const int ql = lane & 31;                   // q (and A-row) lane index
  const int H = lane >> 5;                    // lane half
  const int q0w = qt * 128 + wave * 32;
  const float c2 = 0.18033688f;               // 0.125 * log2(e)

  __shared__ __align__(16) bf16_t sK[64 * 64];     // [kv][d], XOR-swizzled chunks
  __shared__ __align__(16) bf16_t sVT[64 * 64];    // [d][kv], XOR-swizzled chunks

  const bf16_t* vtb = vt + (size_t)bh * 64 * 2048;

  // Q B-frags: frag ks holds Q[q0w+ql][d = 16ks + 8H + j]
  s16x8 qf[4];
  {
    const bf16_t* qrow = qk + (rowbase + q0w + ql) * 2048 + h * 64 + 8 * H;
#pragma unroll
    for (int ks = 0; ks < 4; ++ks) qf[ks] = *(const s16x8*)(qrow + 16 * ks);
  }

  f32x16 oa[2] = {};              // O^T frags: row d = 32df + (r&3)+8(r>>2)+4H, col q=ql
  float lrun = 0.0f;

  for (int kv0 = 0; kv0 < S; kv0 += 64) {
    __syncthreads();
    // stage K [64 kv][64 d] and VT [64 d][64 kv]; swizzled source, linear dest
#pragma unroll
    for (int p = 0; p < 2; ++p) {
      const int c = p * 256 + wave * 64 + lane;
      const int r = c >> 3;
      const int pb = (c & 7) ^ (r & 7);
      char* dK = (char*)sK + (size_t)(p * 256 + wave * 64) * 16;
      char* dV = (char*)sVT + (size_t)(p * 256 + wave * 64) * 16;
      gload_lds16(qk + (rowbase + kv0 + r) * 2048 + 1024 + h * 64 + pb * 8, dK);
      gload_lds16(vtb + (size_t)r * 2048 + kv0 + pb * 8, dV);
    }
    __syncthreads();

    // swapped QK^T: sc[f][r] = S^T[kv = 32f + (r&3)+8(r>>2)+4H][q = ql]
    f32x16 sc[2] = {};
#pragma unroll
    for (int ks = 0; ks < 4; ++ks)
#pragma unroll
      for (int kvf = 0; kvf < 2; ++kvf) {
        const int R = kvf * 32 + ql;
        const s16x8 ak = *(const s16x8*)&sK[R * 64 + (((2 * ks + H) ^ (R & 7)) * 8)];
        sc[kvf] = mfma32(ak, qf[ks], sc[kvf]);
      }

    // fixed-shift softmax: P = exp2(s*c2 - 8); shift cancels in normalization
    float rsum = 0.0f;
#pragma unroll
    for (int f = 0; f < 2; ++f)
#pragma unroll
      for (int r = 0; r < 16; ++r) {
        const float pp = fexp2(fmaf(sc[f][r], c2, -8.0f));
        sc[f][r] = pp;
        rsum += pp;
      }
    rsum += __shfl_xor(rsum, 32);
    lrun += rsum;

    // PV with in-register P B-frags (permlane32_swap with (ql, ql^32) partner)
#pragma unroll
    for (int ks = 0; ks < 4; ++ks) {
      const int f = ks >> 1, rb = (ks & 1) * 8;
      unsigned A1 = pack_bf16(sc[f][rb + 0], sc[f][rb + 1]);
      unsigned A2 = pack_bf16(sc[f][rb + 2], sc[f][rb + 3]);
      unsigned B1 = pack_bf16(sc[f][rb + 4], sc[f][rb + 5]);
      unsigned B2 = pack_bf16(sc[f][rb + 6], sc[f][rb + 7]);
      asm("v_permlane32_swap_b32 %0, %1" : "+v"(A1), "+v"(B1));
      asm("v_permlane32_swap_b32 %0, %1" : "+v"(A2), "+v"(B2));
      union { unsigned u[4]; s16x8 v; } pf;
      pf.u[0] = A1; pf.u[1] = A2; pf.u[2] = B1; pf.u[3] = B2;
      const s16x8 pbf = pf.v;
#pragma unroll
      for (int df = 0; df < 2; ++df) {
        const int R = df * 32 + ql;
        const s16x8 va = *(const s16x8*)&sVT[R * 64 + (((2 * ks + H) ^ (R & 7)) * 8)];
        oa[df] = mfma32(va, pbf, oa[df]);
      }
    }
  }

  const float rl = 1.0f / lrun;
#pragma unroll
  for (int df = 0; df < 2; ++df)
#pragma unroll
    for (int rr = 0; rr < 4; ++rr) {
      bf16x4 ov;
#pragma unroll
      for (int e = 0; e < 4; ++e) ov[e] = (bf16_t)(oa[df][4 * rr + e] * rl);
      const int d0 = 32 * df + 8 * rr + 4 * H;
      *(bf16x4*)&O[(rowbase + q0w + ql) * 1024 + h * 64 + d0] = ov;
    }
}

// ---------------- launch ----------------
extern "C" void kernel_launch(void* const* d_in, const int* in_sizes, int n_in,
                              void* d_out, int out_size, void* d_ws, size_t ws_size,
                              hipStream_t stream) {
  const float* x    = (const float*)d_in[0];
  const float* ln1w = (const float*)d_in[1];
  const float* ln1b = (const float*)d_in[2];
  const float* Wqkv = (const float*)d_in[3];
  const float* bqkv = (const float*)d_in[4];
  const float* Wo   = (const float*)d_in[5];
  const float* bo   = (const float*)d_in[6];
  const float* ln2w = (const float*)d_in[7];
  const float* ln2b = (const float*)d_in[8];
  const float* fc1w = (const float*)d_in[9];
  const float* fc1b = (const float*)d_in[10];
  const float* fc2w = (const float*)d_in[11];
  const float* fc2b = (const float*)d_in[12];

  const int M = 8192;

  char* ws = (char*)d_ws;
  size_t off = 0;
  auto alloc = [&](size_t bytes) {
    char* p = ws + off;
    off += (bytes + 255) & ~(size_t)255;
    return p;
  };
  // persistent weights (bf16, transposed)
  bf16_t* WqkvT = (bf16_t*)alloc((size_t)3072 * 1024 * 2);   // 6 MB
  bf16_t* WoT   = (bf16_t*)alloc((size_t)1024 * 1024 * 2);   // 2 MB
  bf16_t* fc1T  = (bf16_t*)alloc((size_t)4096 * 1024 * 2);   // 8 MB
  bf16_t* fc2T  = (bf16_t*)alloc((size_t)1024 * 4096 * 2);   // 8 MB
  // activations
  bf16_t* h1    = (bf16_t*)alloc((size_t)M * 1024 * 2);      // 16 MB (reused as h2)
  bf16_t* qkQK  = (bf16_t*)alloc((size_t)M * 2048 * 2);      // 32 MB (attn region pt 1)
  bf16_t* vTg   = (bf16_t*)alloc((size_t)M * 1024 * 2);      // 16 MB (pt 2)
  bf16_t* attnO = (bf16_t*)alloc((size_t)M * 1024 * 2);      // 16 MB (pt 3)
  float*  x2    = (float*)alloc((size_t)M * 1024 * 4);       // 32 MB
  // aliases: lifetimes disjoint in stream order
  bf16_t* h2   = h1;     // h1 dead after QKV GEMM
  bf16_t* gbuf = qkQK;   // qkQK/vTg dead after attn, attnO dead after o-proj
  if (off > ws_size) return;  // ~136 MB required

  const dim3 tb(32, 8);
  tcast_kernel<<<dim3(96, 32), tb, 0, stream>>>(Wqkv, WqkvT, 1024, 3072);
  tcast_kernel<<<dim3(32, 32), tb, 0, stream>>>(Wo, WoT, 1024, 1024);
  tcast_kernel<<<dim3(128, 32), tb, 0, stream>>>(fc1w, fc1T, 1024, 4096);
  tcast_kernel<<<dim3(32, 128), tb, 0, stream>>>(fc2w, fc2T, 4096, 1024);

  ln_kernel<<<M, 256, 0, stream>>>(x, ln1w, ln1b, h1);

  gemm128b<3><<<dim3(1536), 256, 0, stream>>>(h1, WqkvT, bqkv, nullptr, qkQK, vTg, M, 3072, 1024);

  flash_attn10<<<dim3(1024), 256, 0, stream>>>(qkQK, vTg, attnO);

  gemm128b<1><<<dim3(512), 256, 0, stream>>>(attnO, WoT, bo, x, x2, nullptr, M, 1024, 1024);

  ln_kernel<<<M, 256, 0, stream>>>(x2, ln2w, ln2b, h2);

  gemm128b<2><<<dim3(2048), 256, 0, stream>>>(h2, fc1T, fc1b, nullptr, gbuf, nullptr, M, 4096, 1024);

  gemm128b<1><<<dim3(512), 256, 0, stream>>>(gbuf, fc2T, fc2b, x2, (float*)d_out, nullptr, M, 1024, 4096);
}

// Round 22
// 363.748 us; speedup vs baseline: 1.0985x; 1.0395x over previous
//
#include <hip/hip_runtime.h>
#include <hip/hip_bf16.h>
#include <math.h>

typedef __bf16 bf16_t;
typedef __bf16 bf16x4 __attribute__((ext_vector_type(4)));
typedef short  s16x8  __attribute__((ext_vector_type(8)));
typedef float  f32x4  __attribute__((ext_vector_type(4)));
typedef float  f32x16 __attribute__((ext_vector_type(16)));

#define DEVINL __device__ __forceinline__

DEVINL void gload_lds16(const void* g, void* l) {
  __builtin_amdgcn_global_load_lds(
      (const __attribute__((address_space(1))) unsigned int*)g,
      (__attribute__((address_space(3))) unsigned int*)l, 16, 0, 0);
}

DEVINL f32x4 mfma16(s16x8 a, s16x8 b, f32x4 c) {
  return __builtin_amdgcn_mfma_f32_16x16x32_bf16(a, b, c, 0, 0, 0);
}

DEVINL f32x16 mfma32(s16x8 a, s16x8 b, f32x16 c) {
  return __builtin_amdgcn_mfma_f32_32x32x16_bf16(a, b, c, 0, 0, 0);
}

DEVINL float fexp2(float x) { return __builtin_amdgcn_exp2f(x); }  // native v_exp_f32

DEVINL unsigned pack_bf16(float lo, float hi) {
  union { bf16_t h[2]; unsigned u; } p;
  p.h[0] = (bf16_t)lo; p.h[1] = (bf16_t)hi;
  return p.u;
}

// ---------------- transpose + cast: W[K][N] f32 -> WT[N][K] bf16 ----------------
__global__ __launch_bounds__(256) void tcast_kernel(const float* __restrict__ W,
                                                    bf16_t* __restrict__ WT,
                                                    int K, int N) {
  __shared__ float tile[32][33];
  const int n0 = blockIdx.x * 32, k0 = blockIdx.y * 32;
  const int tx = threadIdx.x, ty = threadIdx.y;
#pragma unroll
  for (int j = 0; j < 4; ++j)
    tile[ty + j * 8][tx] = W[(size_t)(k0 + ty + j * 8) * N + (n0 + tx)];
  __syncthreads();
#pragma unroll
  for (int j = 0; j < 4; ++j)
    WT[(size_t)(n0 + ty + j * 8) * K + (k0 + tx)] = (bf16_t)tile[tx][ty + j * 8];
}

// ---------------- layernorm: f32 [rows][1024] -> bf16 ----------------
__global__ __launch_bounds__(256) void ln_kernel(const float* __restrict__ x,
                                                 const float* __restrict__ w,
                                                 const float* __restrict__ b,
                                                 bf16_t* __restrict__ out) {
  const int row = blockIdx.x, tid = threadIdx.x;
  const float4 v = ((const float4*)(x + (size_t)row * 1024))[tid];
  float s  = v.x + v.y + v.z + v.w;
  float s2 = v.x * v.x + v.y * v.y + v.z * v.z + v.w * v.w;
#pragma unroll
  for (int off = 32; off > 0; off >>= 1) {
    s  += __shfl_down(s, off);
    s2 += __shfl_down(s2, off);
  }
  __shared__ float red[8];
  const int wave = tid >> 6, lane = tid & 63;
  if (lane == 0) { red[wave] = s; red[4 + wave] = s2; }
  __syncthreads();
  s  = red[0] + red[1] + red[2] + red[3];
  s2 = red[4] + red[5] + red[6] + red[7];
  const float mu = s * (1.0f / 1024.0f);
  const float rs = rsqrtf(s2 * (1.0f / 1024.0f) - mu * mu + 1e-5f);
  const float4 wv = ((const float4*)w)[tid];
  const float4 bv = ((const float4*)b)[tid];
  bf16x4 o;
  o[0] = (bf16_t)((v.x - mu) * rs * wv.x + bv.x);
  o[1] = (bf16_t)((v.y - mu) * rs * wv.y + bv.y);
  o[2] = (bf16_t)((v.z - mu) * rs * wv.z + bv.z);
  o[3] = (bf16_t)((v.w - mu) * rs * wv.w + bv.w);
  ((bf16x4*)(out + (size_t)row * 1024))[tid] = o;
}

// ---------------- 128x128 GEMM, BK=64, TLP-based (r15 winner, unchanged) -----
// m-slice XCD chunking: each XCD owns 8 contiguous m-blocks x ALL n-cols.
// EPI 0: +bias -> bf16 | 1: +bias+resid -> f32 | 2: gelu -> bf16 | 3: qkv split
template <int EPI>
__global__ __launch_bounds__(256, 4) void gemm128b(const bf16_t* __restrict__ A,
                                                   const bf16_t* __restrict__ BT,
                                                   const float* __restrict__ bias,
                                                   const float* __restrict__ resid,
                                                   void* __restrict__ out,
                                                   void* __restrict__ out2,
                                                   int M, int N, int K) {
  __shared__ __align__(16) bf16_t sA[128 * 64];
  __shared__ __align__(16) bf16_t sB[128 * 64];
  const int tid = threadIdx.x;
  const int lane = tid & 63, wave = tid >> 6;
  const int wr = wave >> 1, wc = wave & 1;
  const int g = lane >> 4, lr = lane & 15;

  const int bid = blockIdx.x;
  const int xcd = bid & 7;
  const int i = bid >> 3;          // [0, 8*NB)
  const int m0 = (xcd * 8 + (i & 7)) * 128;
  const int n0 = (i >> 3) * 128;
  const bf16_t* Ab = A + (size_t)m0 * K;
  const bf16_t* Bb = BT + (size_t)n0 * K;

  f32x4 acc[4][4] = {};

  for (int kt = 0; kt < K; kt += 64) {
    __syncthreads();
#pragma unroll
    for (int q = 0; q < 4; ++q) {
      const int c = q * 256 + tid;
      const int r = c >> 3;
      const int j = (c & 7) ^ (r & 7);
      const size_t doff = (size_t)(q * 256 + wave * 64) * 8;
      gload_lds16(Ab + (size_t)r * K + kt + j * 8, sA + doff);
      gload_lds16(Bb + (size_t)r * K + kt + j * 8, sB + doff);
    }
    __syncthreads();
#pragma unroll
    for (int ks = 0; ks < 2; ++ks) {
      s16x8 af[4], bfr[4];
#pragma unroll
      for (int m = 0; m < 4; ++m) {
        const int r = wr * 64 + m * 16 + lr;
        af[m] = *(const s16x8*)&sA[r * 64 + (((ks << 2) + g) ^ (r & 7)) * 8];
      }
#pragma unroll
      for (int n = 0; n < 4; ++n) {
        const int r = wc * 64 + n * 16 + lr;
        bfr[n] = *(const s16x8*)&sB[r * 64 + (((ks << 2) + g) ^ (r & 7)) * 8];
      }
#pragma unroll
      for (int m = 0; m < 4; ++m)
#pragma unroll
        for (int n = 0; n < 4; ++n)
          acc[m][n] = mfma16(af[m], bfr[n], acc[m][n]);
    }
  }

#pragma unroll
  for (int m = 0; m < 4; ++m)
#pragma unroll
    for (int n = 0; n < 4; ++n) {
      const int col = n0 + wc * 64 + n * 16 + lr;
      const float bv = bias[col];
      const int rrow0 = m0 + wr * 64 + m * 16 + g * 4;
      if (EPI == 3 && col >= 2048) {
        const int col2 = col - 2048;
        bf16x4 pk;
#pragma unroll
        for (int i2 = 0; i2 < 4; ++i2) pk[i2] = (bf16_t)(acc[m][n][i2] + bv);
        const size_t didx =
            ((((size_t)(rrow0 >> 11)) * 16 + (col2 >> 6)) * 64 + (col2 & 63)) * 2048 +
            (rrow0 & 2047);
        *(bf16x4*)&((bf16_t*)out2)[didx] = pk;
      } else {
#pragma unroll
        for (int i2 = 0; i2 < 4; ++i2) {
          const int rrow = rrow0 + i2;
          float v = acc[m][n][i2] + bv;
          if (EPI == 1) {
            const size_t idx = (size_t)rrow * N + col;
            v += resid[idx];
            ((float*)out)[idx] = v;
          } else if (EPI == 2) {
            v = 0.5f * v * (1.0f + erff(v * 0.70710678118f));
            ((bf16_t*)out)[(size_t)rrow * N + col] = (bf16_t)v;
          } else if (EPI == 3) {
            ((bf16_t*)out)[(size_t)rrow * 2048 + col] = (bf16_t)v;
          } else {
            ((bf16_t*)out)[(size_t)rrow * N + col] = (bf16_t)v;
          }
        }
      }
    }
}

// ---------------- flash attention v14: KVBLK=128, 2 inner passes -------------
// = v10 core (32x32 MFMA, QBLK=128, in-register P, fixed-shift softmax), but
// each stage/barrier pair loads a 128-kv tile consumed by TWO sequential 64-kv
// compute passes: barrier/drain count per kv halves, register state unchanged.
// sK [128][64] chunk^(r&7); sVT [64][128] (256B rows) chunk^(r&15) -> 2-way.
__global__ __launch_bounds__(256) void flash_attn14(const bf16_t* __restrict__ qk,
                                                    const bf16_t* __restrict__ vt,
                                                    bf16_t* __restrict__ O) {
  const int S = 2048;
  const int bid = blockIdx.x;                 // 1024 blocks
  const int swz = (bid & 7) * 128 + (bid >> 3);
  const int bh = swz >> 4;                    // 64 (b,h)
  const int qt = swz & 15;                    // 16 q-tiles of 128 rows
  const int h = bh & 15;
  const size_t rowbase = (size_t)(bh >> 4) * S;
  const int tid = threadIdx.x, lane = tid & 63, wave = tid >> 6;
  const int ql = lane & 31;                   // q (and A-row) lane index
  const int H = lane >> 5;                    // lane half
  const int q0w = qt * 128 + wave * 32;
  const float c2 = 0.18033688f;               // 0.125 * log2(e)

  __shared__ __align__(16) bf16_t sK[128 * 64];    // [kv][d],  chunk^(row&7)
  __shared__ __align__(16) bf16_t sVT[64 * 128];   // [d][kv],  chunk^(row&15)

  const bf16_t* vtb = vt + (size_t)bh * 64 * 2048;

  // Q B-frags: frag ks holds Q[q0w+ql][d = 16ks + 8H + j]
  s16x8 qf[4];
  {
    const bf16_t* qrow = qk + (rowbase + q0w + ql) * 2048 + h * 64 + 8 * H;
#pragma unroll
    for (int ks = 0; ks < 4; ++ks) qf[ks] = *(const s16x8*)(qrow + 16 * ks);
  }

  f32x16 oa[2] = {};              // O^T frags: row d = 32df + (r&3)+8(r>>2)+4H, col q=ql
  float lrun = 0.0f;

  for (int kv0 = 0; kv0 < S; kv0 += 128) {
    __syncthreads();
    // stage K [128 kv][64 d] (1024 chunks) and VT [64 d][128 kv] (1024 chunks)
#pragma unroll
    for (int p = 0; p < 4; ++p) {
      const int c = p * 256 + wave * 64 + lane;
      // K: row r = c>>3 (0..127), chunk (c&7)^(r&7)
      const int rk = c >> 3;
      const int pk = (c & 7) ^ (rk & 7);
      // VT: row r = c>>4 (0..63), chunk (c&15)^(r&15)
      const int rv = c >> 4;
      const int pv = (c & 15) ^ (rv & 15);
      char* dK = (char*)sK + (size_t)(p * 256 + wave * 64) * 16;
      char* dV = (char*)sVT + (size_t)(p * 256 + wave * 64) * 16;
      gload_lds16(qk + (rowbase + kv0 + rk) * 2048 + 1024 + h * 64 + pk * 8, dK);
      gload_lds16(vtb + (size_t)rv * 2048 + kv0 + pv * 8, dV);
    }
    __syncthreads();

    // two sequential 64-kv compute passes over the staged tile
#pragma unroll
    for (int half = 0; half < 2; ++half) {
      // swapped QK^T: sc[f][r] = S^T[kv = 64*half + 32f + crow][q = ql]
      f32x16 sc[2] = {};
#pragma unroll
      for (int ks = 0; ks < 4; ++ks)
#pragma unroll
        for (int kvf = 0; kvf < 2; ++kvf) {
          const int R = half * 64 + kvf * 32 + ql;
          const s16x8 ak = *(const s16x8*)&sK[R * 64 + (((2 * ks + H) ^ (R & 7)) * 8)];
          sc[kvf] = mfma32(ak, qf[ks], sc[kvf]);
        }

      // fixed-shift softmax: P = exp2(s*c2 - 8); shift cancels in normalization
      float rsum = 0.0f;
#pragma unroll
      for (int f = 0; f < 2; ++f)
#pragma unroll
        for (int r = 0; r < 16; ++r) {
          const float pp = fexp2(fmaf(sc[f][r], c2, -8.0f));
          sc[f][r] = pp;
          rsum += pp;
        }
      rsum += __shfl_xor(rsum, 32);
      lrun += rsum;

      // PV with in-register P B-frags (permlane32_swap with (ql, ql^32) partner)
#pragma unroll
      for (int ks = 0; ks < 4; ++ks) {
        const int f = ks >> 1, rb = (ks & 1) * 8;
        unsigned A1 = pack_bf16(sc[f][rb + 0], sc[f][rb + 1]);
        unsigned A2 = pack_bf16(sc[f][rb + 2], sc[f][rb + 3]);
        unsigned B1 = pack_bf16(sc[f][rb + 4], sc[f][rb + 5]);
        unsigned B2 = pack_bf16(sc[f][rb + 6], sc[f][rb + 7]);
        asm("v_permlane32_swap_b32 %0, %1" : "+v"(A1), "+v"(B1));
        asm("v_permlane32_swap_b32 %0, %1" : "+v"(A2), "+v"(B2));
        union { unsigned u[4]; s16x8 v; } pf;
        pf.u[0] = A1; pf.u[1] = A2; pf.u[2] = B1; pf.u[3] = B2;
        const s16x8 pbf = pf.v;
#pragma unroll
        for (int df = 0; df < 2; ++df) {
          const int R = df * 32 + ql;             // d-row of VT
          const int lc = half * 8 + 2 * ks + H;   // logical 16B chunk in 128-kv row
          const s16x8 va = *(const s16x8*)&sVT[R * 128 + ((lc ^ (R & 15)) * 8)];
          oa[df] = mfma32(va, pbf, oa[df]);
        }
      }
    }
  }

  const float rl = 1.0f / lrun;
#pragma unroll
  for (int df = 0; df < 2; ++df)
#pragma unroll
    for (int rr = 0; rr < 4; ++rr) {
      bf16x4 ov;
#pragma unroll
      for (int e = 0; e < 4; ++e) ov[e] = (bf16_t)(oa[df][4 * rr + e] * rl);
      const int d0 = 32 * df + 8 * rr + 4 * H;
      *(bf16x4*)&O[(rowbase + q0w + ql) * 1024 + h * 64 + d0] = ov;
    }
}

// ---------------- launch ----------------
extern "C" void kernel_launch(void* const* d_in, const int* in_sizes, int n_in,
                              void* d_out, int out_size, void* d_ws, size_t ws_size,
                              hipStream_t stream) {
  const float* x    = (const float*)d_in[0];
  const float* ln1w = (const float*)d_in[1];
  const float* ln1b = (const float*)d_in[2];
  const float* Wqkv = (const float*)d_in[3];
  const float* bqkv = (const float*)d_in[4];
  const float* Wo   = (const float*)d_in[5];
  const float* bo   = (const float*)d_in[6];
  const float* ln2w = (const float*)d_in[7];
  const float* ln2b = (const float*)d_in[8];
  const float* fc1w = (const float*)d_in[9];
  const float* fc1b = (const float*)d_in[10];
  const float* fc2w = (const float*)d_in[11];
  const float* fc2b = (const float*)d_in[12];

  const int M = 8192;

  char* ws = (char*)d_ws;
  size_t off = 0;
  auto alloc = [&](size_t bytes) {
    char* p = ws + off;
    off += (bytes + 255) & ~(size_t)255;
    return p;
  };
  // persistent weights (bf16, transposed)
  bf16_t* WqkvT = (bf16_t*)alloc((size_t)3072 * 1024 * 2);   // 6 MB
  bf16_t* WoT   = (bf16_t*)alloc((size_t)1024 * 1024 * 2);   // 2 MB
  bf16_t* fc1T  = (bf16_t*)alloc((size_t)4096 * 1024 * 2);   // 8 MB
  bf16_t* fc2T  = (bf16_t*)alloc((size_t)1024 * 4096 * 2);   // 8 MB
  // activations
  bf16_t* h1    = (bf16_t*)alloc((size_t)M * 1024 * 2);      // 16 MB (reused as h2)
  bf16_t* qkQK  = (bf16_t*)alloc((size_t)M * 2048 * 2);      // 32 MB (attn region pt 1)
  bf16_t* vTg   = (bf16_t*)alloc((size_t)M * 1024 * 2);      // 16 MB (pt 2)
  bf16_t* attnO = (bf16_t*)alloc((size_t)M * 1024 * 2);      // 16 MB (pt 3)
  float*  x2    = (float*)alloc((size_t)M * 1024 * 4);       // 32 MB
  // aliases: lifetimes disjoint in stream order
  bf16_t* h2   = h1;     // h1 dead after QKV GEMM
  bf16_t* gbuf = qkQK;   // qkQK/vTg dead after attn, attnO dead after o-proj
  if (off > ws_size) return;  // ~136 MB required

  const dim3 tb(32, 8);
  tcast_kernel<<<dim3(96, 32), tb, 0, stream>>>(Wqkv, WqkvT, 1024, 3072);
  tcast_kernel<<<dim3(32, 32), tb, 0, stream>>>(Wo, WoT, 1024, 1024);
  tcast_kernel<<<dim3(128, 32), tb, 0, stream>>>(fc1w, fc1T, 1024, 4096);
  tcast_kernel<<<dim3(32, 128), tb, 0, stream>>>(fc2w, fc2T, 4096, 1024);

  ln_kernel<<<M, 256, 0, stream>>>(x, ln1w, ln1b, h1);

  gemm128b<3><<<dim3(1536), 256, 0, stream>>>(h1, WqkvT, bqkv, nullptr, qkQK, vTg, M, 3072, 1024);

  flash_attn14<<<dim3(1024), 256, 0, stream>>>(qkQK, vTg, attnO);

  gemm128b<1><<<dim3(512), 256, 0, stream>>>(attnO, WoT, bo, x, x2, nullptr, M, 1024, 1024);

  ln_kernel<<<M, 256, 0, stream>>>(x2, ln2w, ln2b, h2);

  gemm128b<2><<<dim3(2048), 256, 0, stream>>>(h2, fc1T, fc1b, nullptr, gbuf, nullptr, M, 4096, 1024);

  gemm128b<1><<<dim3(512), 256, 0, stream>>>(gbuf, fc2T, fc2b, x2, (float*)d_out, nullptr, M, 1024, 4096);
}